// Round 7
// baseline (6266.431 us; speedup 1.0000x reference)
//
#include <hip/hip_runtime.h>

namespace {

constexpr int T_STEPS = 32;
constexpr int BATCH   = 8192;
constexpr int H1      = 480;
constexpr int HID     = 200;
constexpr int H2      = 320;
constexpr int BR      = 16;    // rows per block = one MFMA M-tile
constexpr int NTHR    = 512;   // 8 waves

constexpr int NCH   = 13;      // 16-col chunks covering 208 (>= HID)
constexpr int SL_X  = 15;      // K-slices of 32 for x-part (480)
constexpr int SL_H  = 7;       // K-slices for h-part (224 >= HID)
constexpr int FR_WG = 3 * NCH * SL_X;       // 585
constexpr int FR_UG = 3 * NCH * SL_H;       // 273
constexpr int FR_W2 = (H2 / 16) * SL_H;     // 140
constexpr int FRAGS = FR_WG + FR_UG + FR_W2;  // 998
constexpr size_t WS_NEED = (size_t)FRAGS * 512 * 2;

typedef short  short8 __attribute__((ext_vector_type(8)));
typedef float  f32x4  __attribute__((ext_vector_type(4)));

__device__ __forceinline__ unsigned short f2bf(float x) {
    unsigned u = __float_as_uint(x);
    u = (u + 0x7fffu + ((u >> 16) & 1u)) >> 16;
    return (unsigned short)u;
}
__device__ __forceinline__ float bfu2f(unsigned short b) {
    return __uint_as_float(((unsigned)b) << 16);
}
__device__ __forceinline__ float sigmoid_(float x) { return 1.f / (1.f + __expf(-x)); }
__device__ __forceinline__ float tanh_(float x) {
    x = fminf(fmaxf(x, -15.f), 15.f);
    const float e = __expf(-2.f * x);
    return (1.f - e) / (1.f + e);
}
__device__ __forceinline__ f32x4 MFMA(short8 a, short8 b, f32x4 c) {
    return __builtin_amdgcn_mfma_f32_16x16x32_bf16(a, b, c, 0, 0, 0);
}
// element offset of (k, m-or-n) in slice-linear A/B fragment storage
__device__ __forceinline__ int frag_off(int k, int m) {
    return ((k >> 5) * 64 + ((k & 31) >> 3) * 16 + m) * 8 + (k & 7);
}

// ---- prep: rearrange Wg/Ug/W2 to bf16 B-frag-linear layout in d_ws ----
// WgF: [(g*13+c)*15+s][512] ; UgF: [(g*13+c)*7+s][512] ; W2F: [t*7+s][512]
__global__ void cvt_kernel(const float* __restrict__ Wg, const float* __restrict__ Ug,
                           const float* __restrict__ W2, unsigned short* __restrict__ o) {
    const int i = blockIdx.x * 256 + threadIdx.x;
    if (i >= FRAGS * 512) return;
    const int f = i >> 9, e = i & 511;
    const int l = e >> 3, j = e & 7;
    const int nn = l & 15, q = l >> 4;
    float v = 0.f;
    if (f < FR_WG) {
        const int g = f / (NCH * SL_X), r = f % (NCH * SL_X), c = r / SL_X, s = r % SL_X;
        const int n = 16 * c + nn, k = 32 * s + 8 * q + j;
        if (n < 200) v = Wg[k * 600 + g * 200 + n];
    } else if (f < FR_WG + FR_UG) {
        const int f2 = f - FR_WG;
        const int g = f2 / (NCH * SL_H), r = f2 % (NCH * SL_H), c = r / SL_H, s = r % SL_H;
        const int n = 16 * c + nn, k = 32 * s + 8 * q + j;
        if (n < 200 && k < 200) v = Ug[k * 600 + g * 200 + n];
    } else {
        const int f3 = f - FR_WG - FR_UG, tl = f3 / SL_H, s = f3 % SL_H;
        const int n = 16 * tl + nn, k = 32 * s + 8 * q + j;
        if (k < 200) v = W2[k * 320 + n];
    }
    o[i] = f2bf(v);
}

__global__ __launch_bounds__(NTHR, 4) void knet_mfma(
    const float* __restrict__ y,    // [T,B,2]
    const float* __restrict__ Fm,   // [4,4]
    const float* __restrict__ Hm,   // [2,4]
    const float* __restrict__ W1,   // [8,480]
    const float* __restrict__ b1,   // [480]
    const float* __restrict__ bg,   // [2,600]
    const float* __restrict__ b2,   // [320]
    const float* __restrict__ W3,   // [320,8]
    const float* __restrict__ b3,   // [8]
    const float* __restrict__ hn0,  // [B,200]
    const unsigned short* __restrict__ WF,
    float* __restrict__ out)        // [T,B,4]
{
    __shared__ __align__(16) unsigned short s_a1f[2 * SL_X * 512];  // 30720 B (a2 unions)
    __shared__ __align__(16) unsigned short s_hf[2 * SL_H * 512];   // 14336 B
    __shared__ float s_bz[208], s_br[208], s_bhx[208], s_bhh[208];
    __shared__ float s_b2[H2];
    __shared__ float s_y[T_STEPS][16][2];   // 4 KB, y preloaded once
    __shared__ float s_in8[16][9];
    __shared__ float s_dm1y[16][2], s_prior[16][4], s_post[16][4], s_kg[16][8];

    const int tid  = threadIdx.x;
    const int lane = tid & 63, wv = tid >> 6;   // 8 waves
    const int row0 = blockIdx.x * BR;

    unsigned short* a1h = s_a1f;
    unsigned short* a1l = s_a1f + SL_X * 512;
    unsigned short* hh_ = s_hf;
    unsigned short* hl_ = s_hf + SL_H * 512;
    float* s_a2 = (float*)s_a1f;  // union: 320*16 fp32 = 20480 B <= 30720 B

    const unsigned short* UgF = WF + (size_t)FR_WG * 512;
    const unsigned short* W2F = WF + (size_t)(FR_WG + FR_UG) * 512;

    // ---- init ----
    for (int t = tid; t < 208; t += NTHR) {
        const bool v = t < 200;
        s_bz[t]  = v ? bg[t] + bg[600 + t] : 0.f;
        s_br[t]  = v ? bg[200 + t] + bg[800 + t] : 0.f;
        s_bhx[t] = v ? bg[400 + t] : 0.f;
        s_bhh[t] = v ? bg[1000 + t] : 0.f;
    }
    for (int t = tid; t < H2; t += NTHR) s_b2[t] = b2[t];
    for (int i = tid; i < T_STEPS * 16 * 2; i += NTHR) {  // y slice -> LDS
        const int t = i >> 5, rem = i & 31;
        s_y[t][rem >> 1][rem & 1] = y[((size_t)t * BATCH + row0) * 2 + rem];
    }
    for (int i = tid; i < 224 * 16; i += NTHR) {  // h0 -> hi/lo frags (+zero K-pad)
        const int k = i >> 4, m = i & 15;
        const float hv = (k < 200) ? hn0[(size_t)(row0 + m) * HID + k] : 0.f;
        const unsigned short hb = f2bf(hv);
        const int off = frag_off(k, m);
        hh_[off] = hb;
        hl_[off] = f2bf(hv - bfu2f(hb));
    }
    if (tid < 64) {
        s_prior[tid >> 2][tid & 3] = 0.f;
        s_post[tid >> 2][tid & 3]  = 0.f;
    }
    __syncthreads();

    const int laneo = lane * 8;
    const f32x4 zero4 = {0.f, 0.f, 0.f, 0.f};

    for (int t = 0; t < T_STEPS; ++t) {
        // ---- Phase A: prior / innovation / features (16 threads) ----
        if (tid < 16) {
            const int r = tid;
            float post[4], prevpri[4], pri[4];
#pragma unroll
            for (int m = 0; m < 4; ++m) { post[m] = s_post[r][m]; prevpri[m] = s_prior[r][m]; }
#pragma unroll
            for (int m = 0; m < 4; ++m) {
                float s = 0.f;
#pragma unroll
                for (int j = 0; j < 4; ++j) s += Fm[m * 4 + j] * post[j];
                pri[m] = s;
            }
            float dy[2];
#pragma unroll
            for (int n = 0; n < 2; ++n) {
                float s = 0.f;
#pragma unroll
                for (int m = 0; m < 4; ++m) s += Hm[n * 4 + m] * pri[m];
                dy[n] = s_y[t][r][n] - s;
            }
            float dx[4], ssx = 0.f;
#pragma unroll
            for (int m = 0; m < 4; ++m) { dx[m] = post[m] - prevpri[m]; ssx += dx[m] * dx[m]; }
            const float idx_ = rsqrtf(fmaxf(ssx, 1e-12f));
            const float idy_ = rsqrtf(fmaxf(dy[0] * dy[0] + dy[1] * dy[1], 1e-12f));
            s_in8[r][0] = dy[0] * idy_;
            s_in8[r][1] = dy[1] * idy_;
            s_in8[r][2] = dy[0] * idy_;
            s_in8[r][3] = dy[1] * idy_;
#pragma unroll
            for (int m = 0; m < 4; ++m) s_in8[r][4 + m] = dx[m] * idx_;
            s_dm1y[r][0] = dy[0];
            s_dm1y[r][1] = dy[1];
#pragma unroll
            for (int m = 0; m < 4; ++m) s_prior[r][m] = pri[m];
        }
        __syncthreads();

        // ---- Phase B: a1 = relu(in8 @ W1), hi/lo split into A-frag layout ----
        {
            const int m = tid & 15;
            float v8[8];
#pragma unroll
            for (int k = 0; k < 8; ++k) v8[k] = s_in8[m][k];
            for (int it = 0; it < 15; ++it) {
                const int j = (tid >> 4) + 32 * it;  // 0..479
                float s = b1[j];
#pragma unroll
                for (int k = 0; k < 8; ++k) s = fmaf(v8[k], W1[k * H1 + j], s);
                s = fmaxf(s, 0.f);
                const unsigned short hb = f2bf(s);
                const int off = frag_off(j, m);
                a1h[off] = hb;
                a1l[off] = f2bf(s - bfu2f(hb));
            }
        }
        __syncthreads();

        // ---- GRU merged pass: per chunk all 4 gate accumulators (3-way MFMA ILP) ----
        f32x4 hstash[2];
#pragma unroll
        for (int q = 0; q < 2; ++q) {
            hstash[q] = zero4;
            const int c = wv + 8 * q;     // 2 chunks per wave, balanced
            if (c < NCH) {
                f32x4 az = zero4, ar = zero4, ax = zero4, ah = zero4;
                const unsigned short* fz = WF + (size_t)((0 * NCH + c) * SL_X) * 512 + laneo;
                const unsigned short* fr = WF + (size_t)((1 * NCH + c) * SL_X) * 512 + laneo;
                const unsigned short* fx = WF + (size_t)((2 * NCH + c) * SL_X) * 512 + laneo;
                for (int s = 0; s < SL_X; ++s) {
                    const short8 Ahi = *(const short8*)(a1h + s * 512 + laneo);
                    const short8 Alo = *(const short8*)(a1l + s * 512 + laneo);
                    const short8 Bz = *(const short8*)(fz + s * 512);
                    const short8 Br = *(const short8*)(fr + s * 512);
                    const short8 Bx = *(const short8*)(fx + s * 512);
                    az = MFMA(Alo, Bz, az);
                    ar = MFMA(Alo, Br, ar);
                    ax = MFMA(Alo, Bx, ax);
                    az = MFMA(Ahi, Bz, az);
                    ar = MFMA(Ahi, Br, ar);
                    ax = MFMA(Ahi, Bx, ax);
                }
                const unsigned short* gz = UgF + (size_t)((0 * NCH + c) * SL_H) * 512 + laneo;
                const unsigned short* gr = UgF + (size_t)((1 * NCH + c) * SL_H) * 512 + laneo;
                const unsigned short* gh = UgF + (size_t)((2 * NCH + c) * SL_H) * 512 + laneo;
                for (int s = 0; s < SL_H; ++s) {
                    const short8 Ahi = *(const short8*)(hh_ + s * 512 + laneo);
                    const short8 Alo = *(const short8*)(hl_ + s * 512 + laneo);
                    const short8 Bz = *(const short8*)(gz + s * 512);
                    const short8 Br = *(const short8*)(gr + s * 512);
                    const short8 Bh = *(const short8*)(gh + s * 512);
                    az = MFMA(Alo, Bz, az);
                    ar = MFMA(Alo, Br, ar);
                    ah = MFMA(Alo, Bh, ah);
                    az = MFMA(Ahi, Bz, az);
                    ar = MFMA(Ahi, Br, ar);
                    ah = MFMA(Ahi, Bh, ah);
                }
                const int n  = 16 * c + (lane & 15);
                const float bz = s_bz[n], br = s_br[n], bx = s_bhx[n], bh = s_bhh[n];
#pragma unroll
                for (int i = 0; i < 4; ++i) {
                    const int m   = (lane >> 4) * 4 + i;
                    const int off = frag_off(n, m);
                    const float hold = bfu2f(hh_[off]) + bfu2f(hl_[off]);
                    const float z  = sigmoid_(az[i] + bz);
                    const float rr = sigmoid_(ar[i] + br);
                    const float hc = tanh_((ax[i] + bx) + rr * (ah[i] + bh));
                    hstash[q][i] = z * hold + (1.f - z) * hc;
                }
            }
        }
        __syncthreads();  // all reads of old h / a1 frags complete

#pragma unroll
        for (int q = 0; q < 2; ++q) {
            const int c = wv + 8 * q;
            if (c < NCH) {
                const int n = 16 * c + (lane & 15);
                if (n < 200) {
#pragma unroll
                    for (int i = 0; i < 4; ++i) {
                        const int m   = (lane >> 4) * 4 + i;
                        const int off = frag_off(n, m);
                        const float hn = hstash[q][i];
                        const unsigned short hb = f2bf(hn);
                        hh_[off] = hb;
                        hl_[off] = f2bf(hn - bfu2f(hb));
                    }
                }
            }
        }
        __syncthreads();  // new h visible (K-pad rows stay zero)

        // ---- P3: a2 = relu(h @ W2); 20 N-tiles over 8 waves ----
#pragma unroll
        for (int q = 0; q < 3; ++q) {
            const int tl = wv + 8 * q;  // 0..23
            if (tl < 20) {
                f32x4 acc = zero4;
                const unsigned short* fb = W2F + (size_t)(tl * SL_H) * 512 + laneo;
                for (int s = 0; s < SL_H; ++s) {
                    const short8 Ahi = *(const short8*)(hh_ + s * 512 + laneo);
                    const short8 Alo = *(const short8*)(hl_ + s * 512 + laneo);
                    const short8 B  = *(const short8*)(fb + s * 512);
                    acc = MFMA(Alo, B, acc);
                    acc = MFMA(Ahi, B, acc);
                }
                const int n  = 16 * tl + (lane & 15);
                const float bb = s_b2[n];
                f32x4 o;
#pragma unroll
                for (int i = 0; i < 4; ++i) o[i] = fmaxf(acc[i] + bb, 0.f);
                *(f32x4*)(s_a2 + n * 16 + (lane >> 4) * 4) = o;  // overwrites a1 frags (dead)
            }
        }
        __syncthreads();

        // ---- Phase E: KG = a2 @ W3 + b3 (VALU, 128 threads, 4-way unroll) ----
        if (tid < 128) {
            const int r = tid >> 3, c = tid & 7;
            float a0 = 0.f, a1_ = 0.f, a2_ = 0.f, a3 = 0.f;
            for (int k = 0; k < H2; k += 4) {
                a0  = fmaf(s_a2[(k + 0) * 16 + r], W3[(k + 0) * 8 + c], a0);
                a1_ = fmaf(s_a2[(k + 1) * 16 + r], W3[(k + 1) * 8 + c], a1_);
                a2_ = fmaf(s_a2[(k + 2) * 16 + r], W3[(k + 2) * 8 + c], a2_);
                a3  = fmaf(s_a2[(k + 3) * 16 + r], W3[(k + 3) * 8 + c], a3);
            }
            s_kg[r][c] = ((a0 + a1_) + (a2_ + a3)) + b3[c];
        }
        __syncthreads();

        // ---- Phase F: posterior update + output ----
        if (tid < 16) {
            const int r = tid;
            const float d0 = s_dm1y[r][0], d1 = s_dm1y[r][1];
            float p[4];
#pragma unroll
            for (int m = 0; m < 4; ++m) {
                p[m] = s_prior[r][m] + s_kg[r][2 * m] * d0 + s_kg[r][2 * m + 1] * d1;
                s_post[r][m] = p[m];
            }
            *reinterpret_cast<float4*>(&out[((size_t)t * BATCH + row0 + r) * 4]) =
                *reinterpret_cast<const float4*>(p);
        }
        __syncthreads();
    }
}

// ================= scalar fp32 fallback (R2-verified structure) =================
constexpr int FBR = 8;
__device__ __forceinline__ void load8f(const float* __restrict__ p, float* a) {
    const float4* v = reinterpret_cast<const float4*>(p);
    const float4 t0 = v[0], t1 = v[1];
    a[0] = t0.x; a[1] = t0.y; a[2] = t0.z; a[3] = t0.w;
    a[4] = t1.x; a[5] = t1.y; a[6] = t1.z; a[7] = t1.w;
}
__global__ __launch_bounds__(256, 4) void knet_fb(
    const float* __restrict__ y, const float* __restrict__ Fm, const float* __restrict__ Hm,
    const float* __restrict__ W1, const float* __restrict__ b1, const float* __restrict__ Wg,
    const float* __restrict__ Ug, const float* __restrict__ bg, const float* __restrict__ W2,
    const float* __restrict__ b2, const float* __restrict__ W3, const float* __restrict__ b3,
    const float* __restrict__ hn0, float* __restrict__ out) {
    __shared__ float s_hnt[HID][FBR];
    __shared__ float s_act[H1][FBR];
    __shared__ float s_in8[FBR][9], s_dm1y[FBR][2], s_prior[FBR][4], s_post[FBR][4], s_kg[FBR][8];
    const int tid = threadIdx.x;
    const int row0 = blockIdx.x * FBR;
    for (int idx = tid; idx < FBR * HID; idx += 256) {
        const int r = idx / HID, k = idx - r * HID;
        s_hnt[k][r] = hn0[(size_t)(row0 + r) * HID + k];
    }
    if (tid < FBR * 4) { s_prior[tid >> 2][tid & 3] = 0.f; s_post[tid >> 2][tid & 3] = 0.f; }
    __syncthreads();
    for (int t = 0; t < T_STEPS; ++t) {
        if (tid < FBR) {
            const int r = tid;
            float post[4], prevpri[4], pri[4];
            for (int m = 0; m < 4; ++m) { post[m] = s_post[r][m]; prevpri[m] = s_prior[r][m]; }
            for (int m = 0; m < 4; ++m) {
                float s = 0.f;
                for (int j = 0; j < 4; ++j) s += Fm[m * 4 + j] * post[j];
                pri[m] = s;
            }
            float dy[2];
            for (int n = 0; n < 2; ++n) {
                float s = 0.f;
                for (int m = 0; m < 4; ++m) s += Hm[n * 4 + m] * pri[m];
                dy[n] = y[((size_t)t * BATCH + row0 + r) * 2 + n] - s;
            }
            float dx[4], ssx = 0.f;
            for (int m = 0; m < 4; ++m) { dx[m] = post[m] - prevpri[m]; ssx += dx[m] * dx[m]; }
            const float idx_ = rsqrtf(fmaxf(ssx, 1e-12f));
            const float idy_ = rsqrtf(fmaxf(dy[0] * dy[0] + dy[1] * dy[1], 1e-12f));
            s_in8[r][0] = dy[0] * idy_; s_in8[r][1] = dy[1] * idy_;
            s_in8[r][2] = dy[0] * idy_; s_in8[r][3] = dy[1] * idy_;
            for (int m = 0; m < 4; ++m) s_in8[r][4 + m] = dx[m] * idx_;
            s_dm1y[r][0] = dy[0]; s_dm1y[r][1] = dy[1];
            for (int m = 0; m < 4; ++m) s_prior[r][m] = pri[m];
        }
        __syncthreads();
        {
            const int r = tid & (FBR - 1);
            float v[8];
            for (int k = 0; k < 8; ++k) v[k] = s_in8[r][k];
            for (int j = tid >> 3; j < H1; j += 32) {
                float s = b1[j];
                for (int k = 0; k < 8; ++k) s = fmaf(v[k], W1[k * H1 + j], s);
                s_act[j][r] = fmaxf(s, 0.f);
            }
        }
        __syncthreads();
        float hnew[FBR];
        if (tid < HID) {
            const int j = tid;
            float az[FBR], arr[FBR], ahx[FBR], ahh[FBR];
            for (int r = 0; r < FBR; ++r) { az[r] = arr[r] = ahx[r] = ahh[r] = 0.f; }
            for (int k = 0; k < H1; ++k) {
                const float wz = Wg[k * 600 + j], wr = Wg[k * 600 + j + HID], wh = Wg[k * 600 + j + 2 * HID];
                float a[FBR];
                load8f(&s_act[k][0], a);
                for (int r = 0; r < FBR; ++r) {
                    az[r] = fmaf(a[r], wz, az[r]); arr[r] = fmaf(a[r], wr, arr[r]); ahx[r] = fmaf(a[r], wh, ahx[r]);
                }
            }
            for (int k = 0; k < HID; ++k) {
                const float uz = Ug[k * 600 + j], ur = Ug[k * 600 + j + HID], uh = Ug[k * 600 + j + 2 * HID];
                float h[FBR];
                load8f(&s_hnt[k][0], h);
                for (int r = 0; r < FBR; ++r) {
                    az[r] = fmaf(h[r], uz, az[r]); arr[r] = fmaf(h[r], ur, arr[r]); ahh[r] = fmaf(h[r], uh, ahh[r]);
                }
            }
            const float bz = bg[j] + bg[600 + j], brr = bg[HID + j] + bg[600 + HID + j];
            const float bhx = bg[2 * HID + j], bhh = bg[600 + 2 * HID + j];
            float ho[FBR];
            load8f(&s_hnt[j][0], ho);
            for (int r = 0; r < FBR; ++r) {
                const float z = sigmoid_(az[r] + bz), rr = sigmoid_(arr[r] + brr);
                const float hc = tanh_((ahx[r] + bhx) + rr * (ahh[r] + bhh));
                hnew[r] = z * ho[r] + (1.f - z) * hc;
            }
        }
        __syncthreads();
        if (tid < HID) {
            float4* dst = reinterpret_cast<float4*>(&s_hnt[tid][0]);
            const float4* src = reinterpret_cast<const float4*>(hnew);
            dst[0] = src[0]; dst[1] = src[1];
        }
        __syncthreads();
        for (int j = tid; j < H2; j += 256) {
            float acc[FBR];
            for (int r = 0; r < FBR; ++r) acc[r] = 0.f;
            for (int k = 0; k < HID; ++k) {
                const float w = W2[k * H2 + j];
                float h[FBR];
                load8f(&s_hnt[k][0], h);
                for (int r = 0; r < FBR; ++r) acc[r] = fmaf(h[r], w, acc[r]);
            }
            for (int r = 0; r < FBR; ++r) s_act[j][r] = fmaxf(acc[r] + b2[j], 0.f);
        }
        __syncthreads();
        if (tid < FBR * 8) {
            const int r = tid >> 3, c = tid & 7;
            float acc = b3[c];
            for (int k = 0; k < H2; ++k) acc = fmaf(s_act[k][r], W3[k * 8 + c], acc);
            s_kg[r][c] = acc;
        }
        __syncthreads();
        if (tid < FBR) {
            const int r = tid;
            const float d0 = s_dm1y[r][0], d1 = s_dm1y[r][1];
            float p[4];
            for (int m = 0; m < 4; ++m) {
                p[m] = s_prior[r][m] + s_kg[r][2 * m] * d0 + s_kg[r][2 * m + 1] * d1;
                s_post[r][m] = p[m];
            }
            *reinterpret_cast<float4*>(&out[((size_t)t * BATCH + row0 + r) * 4]) =
                *reinterpret_cast<const float4*>(p);
        }
        __syncthreads();
    }
}

}  // namespace

extern "C" void kernel_launch(void* const* d_in, const int* in_sizes, int n_in,
                              void* d_out, int out_size, void* d_ws, size_t ws_size,
                              hipStream_t stream) {
    const float* y   = (const float*)d_in[0];
    const float* Fm  = (const float*)d_in[1];
    const float* Hm  = (const float*)d_in[2];
    const float* W1  = (const float*)d_in[3];
    const float* b1  = (const float*)d_in[4];
    const float* Wg  = (const float*)d_in[5];
    const float* Ug  = (const float*)d_in[6];
    const float* bg  = (const float*)d_in[7];
    const float* W2  = (const float*)d_in[8];
    const float* b2  = (const float*)d_in[9];
    const float* W3  = (const float*)d_in[10];
    const float* b3  = (const float*)d_in[11];
    const float* hn0 = (const float*)d_in[12];
    float* out = (float*)d_out;

    if (ws_size >= WS_NEED) {
        unsigned short* WFr = (unsigned short*)d_ws;
        cvt_kernel<<<(FRAGS * 512 + 255) / 256, 256, 0, stream>>>(Wg, Ug, W2, WFr);
        knet_mfma<<<dim3(BATCH / BR), dim3(NTHR), 0, stream>>>(
            y, Fm, Hm, W1, b1, bg, b2, W3, b3, hn0, WFr, out);
    } else {
        knet_fb<<<dim3(BATCH / FBR), dim3(256), 0, stream>>>(
            y, Fm, Hm, W1, b1, Wg, Ug, bg, W2, b2, W3, b3, hn0, out);
    }
}